// Round 2
// baseline (2460.065 us; speedup 1.0000x reference)
//
#include <hip/hip_runtime.h>
#include <hip/hip_bf16.h>

typedef __hip_bfloat16 bf16;

__device__ __forceinline__ float b2f(bf16 v) { return __bfloat162float(v); }
__device__ __forceinline__ bf16  f2b(float v) { return __float2bfloat16(v); }

#define BN_EPS 1e-5f

// ---------------------------------------------------------------------------
// Kernel 1: patchify conv (2x2, stride 2) + BN(eval).  fp32 in -> bf16 qkv.
//   GEMM view: C[co][n] = sum_k A[co][k] * B[k][n]
//   A = w_qkv viewed as [768][1024] row-major (k = ci*4 + kh*2 + kw matches
//   OIHW flat layout exactly). B = im2col of x.
//   Block: 64 co x 64 ow tile for one (b, oh). Grid (12, 16*64).
// ---------------------------------------------------------------------------
__global__ __launch_bounds__(256) void k_conv_qkv(
    const float* __restrict__ x,       // [16,256,128,128] fp32
    const float* __restrict__ w,       // [768,1024] fp32
    const float* __restrict__ gamma1,  // [768] fp32
    const float* __restrict__ beta1,   // [768] fp32
    bf16* __restrict__ qkv)            // [16,768,64,64] bf16
{
    const int co0 = blockIdx.x * 64;
    const int b   = blockIdx.y >> 6;
    const int oh  = blockIdx.y & 63;
    const int tid = threadIdx.x;
    const int ty = tid >> 4, tx = tid & 15;

    __shared__ float sA[64][33];   // [co_local][kk], +1 pad
    __shared__ float sB[32][64];   // [kk][ow]

    float acc[4][4] = {};

    for (int kt = 0; kt < 32; ++kt) {
        const int k0 = kt * 32;
        // A tile: 64x32, coalesced along kk
        #pragma unroll
        for (int i = 0; i < 8; ++i) {
            const int e = tid + i * 256;
            const int co_l = e >> 5, kk = e & 31;
            sA[co_l][kk] = w[(co0 + co_l) * 1024 + k0 + kk];
        }
        // B tile: 32x64 im2col gather
        #pragma unroll
        for (int i = 0; i < 8; ++i) {
            const int e  = tid + i * 256;
            const int kk = e >> 6, ow = e & 63;
            const int k  = k0 + kk;
            const int ci = k >> 2, kh = (k >> 1) & 1, kw = k & 1;
            sB[kk][ow] = x[((b * 256 + ci) * 128 + 2 * oh + kh) * 128 + 2 * ow + kw];
        }
        __syncthreads();
        #pragma unroll
        for (int kk = 0; kk < 32; ++kk) {
            const float a0 = sA[ty * 4 + 0][kk];
            const float a1 = sA[ty * 4 + 1][kk];
            const float a2 = sA[ty * 4 + 2][kk];
            const float a3 = sA[ty * 4 + 3][kk];
            const float4 bv = *(const float4*)&sB[kk][tx * 4];
            acc[0][0] += a0 * bv.x; acc[0][1] += a0 * bv.y; acc[0][2] += a0 * bv.z; acc[0][3] += a0 * bv.w;
            acc[1][0] += a1 * bv.x; acc[1][1] += a1 * bv.y; acc[1][2] += a1 * bv.z; acc[1][3] += a1 * bv.w;
            acc[2][0] += a2 * bv.x; acc[2][1] += a2 * bv.y; acc[2][2] += a2 * bv.z; acc[2][3] += a2 * bv.w;
            acc[3][0] += a3 * bv.x; acc[3][1] += a3 * bv.y; acc[3][2] += a3 * bv.z; acc[3][3] += a3 * bv.w;
        }
        __syncthreads();
    }

    const float inv = rsqrtf(1.0f + BN_EPS);
    #pragma unroll
    for (int i = 0; i < 4; ++i) {
        const int co = co0 + ty * 4 + i;
        const float sc = gamma1[co] * inv;
        const float bt = beta1[co];
        #pragma unroll
        for (int j = 0; j < 4; ++j) {
            const int ow = tx * 4 + j;
            qkv[(b * 768 + co) * 4096 + oh * 64 + ow] = f2b(acc[i][j] * sc + bt);
        }
    }
}

// ---------------------------------------------------------------------------
// Kernel 2/3: axial attention (templated).  bf16 qkv -> bf16 vcat, fp32 acc.
//   MODE 0 (h-attn): per (b, h=fix): S[ky][qx] = sum_c K[c][ky]*Q[c][qx]*scale
//     with elem(c,i) = t[b,c,fix,i]; softmax over ky; out[c][qx] =
//     sum_w V[c][w]*P[w][qx]; store vcat[b][c][fix][qx] (channels 0..255).
//   MODE 1 (w-attn): elem(c,i) = t[b,c,i,fix] (i indexes h);
//     store vcat[b][256+c][qx][fix].
// ---------------------------------------------------------------------------
template <int MODE>
__global__ __launch_bounds__(256) void k_attn(
    const bf16* __restrict__ qkv,     // [16,768,64,64]
    bf16* __restrict__ vcat)          // [16,512,64,64]
{
    const int b   = blockIdx.x >> 6;
    const int fix = blockIdx.x & 63;
    const int tid = threadIdx.x;
    const int ty = tid >> 4, tx = tid & 15;

    const bf16* qb = qkv + (size_t)b * 768 * 4096;
    const bf16* kb = qb + 256 * 4096;
    const bf16* vb = qb + 512 * 4096;

    __shared__ float sS[64][64];      // scores then probs, [key][query]
    __shared__ float sK[16][64];
    __shared__ float sQ[16][64];
    __shared__ float sV[64][65];      // +1 pad

    // ---- Phase A: S = K^T Q * scale ----
    float acc[4][4] = {};
    for (int cc0 = 0; cc0 < 256; cc0 += 16) {
        #pragma unroll
        for (int i = 0; i < 4; ++i) {
            const int e = tid + i * 256;
            const int c_l = e >> 6, ii = e & 63;
            const int c = cc0 + c_l;
            const int idx = (MODE == 0) ? (c * 4096 + fix * 64 + ii)
                                        : (c * 4096 + ii * 64 + fix);
            sK[c_l][ii] = b2f(kb[idx]);
            sQ[c_l][ii] = b2f(qb[idx]);
        }
        __syncthreads();
        #pragma unroll
        for (int cc = 0; cc < 16; ++cc) {
            const float4 kv = *(const float4*)&sK[cc][ty * 4];
            const float4 qv = *(const float4*)&sQ[cc][tx * 4];
            acc[0][0] += kv.x * qv.x; acc[0][1] += kv.x * qv.y; acc[0][2] += kv.x * qv.z; acc[0][3] += kv.x * qv.w;
            acc[1][0] += kv.y * qv.x; acc[1][1] += kv.y * qv.y; acc[1][2] += kv.y * qv.z; acc[1][3] += kv.y * qv.w;
            acc[2][0] += kv.z * qv.x; acc[2][1] += kv.z * qv.y; acc[2][2] += kv.z * qv.z; acc[2][3] += kv.z * qv.w;
            acc[3][0] += kv.w * qv.x; acc[3][1] += kv.w * qv.y; acc[3][2] += kv.w * qv.z; acc[3][3] += kv.w * qv.w;
        }
        __syncthreads();
    }
    #pragma unroll
    for (int i = 0; i < 4; ++i)
        #pragma unroll
        for (int j = 0; j < 4; ++j)
            sS[ty * 4 + i][tx * 4 + j] = acc[i][j] * 0.0625f;  // 1/sqrt(256)
    __syncthreads();

    // ---- softmax over key axis (rows of sS), one column per thread ----
    if (tid < 64) {
        float m = -1e30f;
        for (int w = 0; w < 64; ++w) m = fmaxf(m, sS[w][tid]);
        float s = 0.f;
        for (int w = 0; w < 64; ++w) {
            const float e = __expf(sS[w][tid] - m);
            sS[w][tid] = e;
            s += e;
        }
        const float r = 1.0f / s;
        for (int w = 0; w < 64; ++w) sS[w][tid] *= r;
    }
    __syncthreads();

    // ---- Phase B: out = V @ P, 64 channels per chunk ----
    for (int ch = 0; ch < 4; ++ch) {
        #pragma unroll
        for (int i = 0; i < 16; ++i) {
            const int e = tid + i * 256;
            const int c_l = e >> 6, ww = e & 63;
            const int c = ch * 64 + c_l;
            const int idx = (MODE == 0) ? (c * 4096 + fix * 64 + ww)
                                        : (c * 4096 + ww * 64 + fix);
            sV[c_l][ww] = b2f(vb[idx]);
        }
        __syncthreads();
        float o[4][4] = {};
        #pragma unroll
        for (int w = 0; w < 64; ++w) {
            const float v0 = sV[ty * 4 + 0][w];
            const float v1 = sV[ty * 4 + 1][w];
            const float v2 = sV[ty * 4 + 2][w];
            const float v3 = sV[ty * 4 + 3][w];
            const float4 pv = *(const float4*)&sS[w][tx * 4];
            o[0][0] += v0 * pv.x; o[0][1] += v0 * pv.y; o[0][2] += v0 * pv.z; o[0][3] += v0 * pv.w;
            o[1][0] += v1 * pv.x; o[1][1] += v1 * pv.y; o[1][2] += v1 * pv.z; o[1][3] += v1 * pv.w;
            o[2][0] += v2 * pv.x; o[2][1] += v2 * pv.y; o[2][2] += v2 * pv.z; o[2][3] += v2 * pv.w;
            o[3][0] += v3 * pv.x; o[3][1] += v3 * pv.y; o[3][2] += v3 * pv.z; o[3][3] += v3 * pv.w;
        }
        #pragma unroll
        for (int i = 0; i < 4; ++i) {
            const int c = ch * 64 + ty * 4 + i;
            #pragma unroll
            for (int j = 0; j < 4; ++j) {
                const int qx = tx * 4 + j;
                const int oidx = (MODE == 0)
                    ? ((b * 512 + c) * 4096 + fix * 64 + qx)        // v_h
                    : ((b * 512 + 256 + c) * 4096 + qx * 64 + fix); // v_w
                vcat[oidx] = f2b(o[i][j]);
            }
        }
        __syncthreads();
    }
}

// ---------------------------------------------------------------------------
// Kernel 4: 1x1 proj conv + BN + ReLU. bf16 vcat, fp32 weights -> fp32 out.
//   GEMM M=256, K=512, N=4096 per batch.
// ---------------------------------------------------------------------------
__global__ __launch_bounds__(256) void k_proj(
    const bf16* __restrict__ vcat,     // [16,512,4096] bf16
    const float* __restrict__ wp,      // [256,512] fp32
    const float* __restrict__ gamma2,  // [256] fp32
    const float* __restrict__ beta2,   // [256] fp32
    float* __restrict__ out)           // [16,256,4096] fp32
{
    const int co0 = blockIdx.x * 64;
    const int b   = blockIdx.y >> 6;
    const int s0  = (blockIdx.y & 63) * 64;
    const int tid = threadIdx.x;
    const int ty = tid >> 4, tx = tid & 15;

    __shared__ float sA[64][33];
    __shared__ float sB[32][64];

    float acc[4][4] = {};

    for (int kt = 0; kt < 16; ++kt) {
        const int k0 = kt * 32;
        #pragma unroll
        for (int i = 0; i < 8; ++i) {
            const int e = tid + i * 256;
            const int co_l = e >> 5, kk = e & 31;
            sA[co_l][kk] = wp[(co0 + co_l) * 512 + k0 + kk];
        }
        #pragma unroll
        for (int i = 0; i < 8; ++i) {
            const int e = tid + i * 256;
            const int kk = e >> 6, j = e & 63;
            sB[kk][j] = b2f(vcat[(b * 512 + k0 + kk) * 4096 + s0 + j]);
        }
        __syncthreads();
        #pragma unroll
        for (int kk = 0; kk < 32; ++kk) {
            const float a0 = sA[ty * 4 + 0][kk];
            const float a1 = sA[ty * 4 + 1][kk];
            const float a2 = sA[ty * 4 + 2][kk];
            const float a3 = sA[ty * 4 + 3][kk];
            const float4 bv = *(const float4*)&sB[kk][tx * 4];
            acc[0][0] += a0 * bv.x; acc[0][1] += a0 * bv.y; acc[0][2] += a0 * bv.z; acc[0][3] += a0 * bv.w;
            acc[1][0] += a1 * bv.x; acc[1][1] += a1 * bv.y; acc[1][2] += a1 * bv.z; acc[1][3] += a1 * bv.w;
            acc[2][0] += a2 * bv.x; acc[2][1] += a2 * bv.y; acc[2][2] += a2 * bv.z; acc[2][3] += a2 * bv.w;
            acc[3][0] += a3 * bv.x; acc[3][1] += a3 * bv.y; acc[3][2] += a3 * bv.z; acc[3][3] += a3 * bv.w;
        }
        __syncthreads();
    }

    const float inv = rsqrtf(1.0f + BN_EPS);
    #pragma unroll
    for (int i = 0; i < 4; ++i) {
        const int co = co0 + ty * 4 + i;
        const float sc = gamma2[co] * inv;
        const float bt = beta2[co];
        #pragma unroll
        for (int j = 0; j < 4; ++j) {
            const float v = acc[i][j] * sc + bt;
            out[(b * 256 + co) * 4096 + s0 + tx * 4 + j] = fmaxf(v, 0.f);
        }
    }
}

// ---------------------------------------------------------------------------
extern "C" void kernel_launch(void* const* d_in, const int* in_sizes, int n_in,
                              void* d_out, int out_size, void* d_ws, size_t ws_size,
                              hipStream_t stream) {
    const float* x      = (const float*)d_in[0];
    const float* w_qkv  = (const float*)d_in[1];
    const float* gamma1 = (const float*)d_in[2];
    const float* beta1  = (const float*)d_in[3];
    const float* w_proj = (const float*)d_in[4];
    const float* gamma2 = (const float*)d_in[5];
    const float* beta2  = (const float*)d_in[6];
    float* out = (float*)d_out;

    // workspace: qkv [16,768,64,64] bf16 (96 MiB), vcat [16,512,64,64] bf16 (64 MiB)
    bf16* qkv  = (bf16*)d_ws;
    bf16* vcat = (bf16*)((char*)d_ws + (size_t)16 * 768 * 4096 * sizeof(bf16));

    k_conv_qkv<<<dim3(12, 16 * 64), 256, 0, stream>>>(x, w_qkv, gamma1, beta1, qkv);
    k_attn<0><<<dim3(16 * 64), 256, 0, stream>>>(qkv, vcat);
    k_attn<1><<<dim3(16 * 64), 256, 0, stream>>>(qkv, vcat);
    k_proj<<<dim3(4, 16 * 64), 256, 0, stream>>>(vcat, w_proj, gamma2, beta2, out);
}

// Round 3
// 1204.478 us; speedup vs baseline: 2.0424x; 2.0424x over previous
//
#include <hip/hip_runtime.h>
#include <hip/hip_bf16.h>

typedef __hip_bfloat16 bf16;
typedef unsigned short u16;
typedef __attribute__((ext_vector_type(8))) short short8;
typedef __attribute__((ext_vector_type(4))) float f32x4;

#define BN_EPS 1e-5f

__device__ __forceinline__ float b2f(bf16 v) { return __bfloat162float(v); }
__device__ __forceinline__ bf16  f2b(float v) { return __float2bfloat16(v); }
__device__ __forceinline__ u16 f2bs(float f) {
    bf16 h = __float2bfloat16(f);
    u16 s; __builtin_memcpy(&s, &h, 2); return s;
}
// async global->LDS, 16 B per lane. LDS dst = wave-uniform base + lane*16.
__device__ __forceinline__ void gl_lds16(const void* g, void* l) {
    __builtin_amdgcn_global_load_lds(
        (const __attribute__((address_space(1))) unsigned int*)g,
        (__attribute__((address_space(3))) unsigned int*)l, 16, 0, 0);
}

// ---------------------------------------------------------------------------
// Patchify: x fp32 [16,256,128,128] -> xt bf16 [n][k] for half a batch.
//   n = (b-b_base)*4096 + oh*64 + ow  (32768 rows), k = ci*4 + kh*2 + kw (1024).
//   Stride==kernel==2 => pure permutation (each x element used exactly once).
// ---------------------------------------------------------------------------
__global__ __launch_bounds__(256) void k_patchify(
    const float* __restrict__ x, u16* __restrict__ xt, int b_base)
{
    const int blk = blockIdx.x;              // 512 = 8 b * 64 oh
    const int b_rel = blk >> 6, oh = blk & 63;
    const int b = b_base + b_rel;
    const int ow = threadIdx.x & 63, ci0 = threadIdx.x >> 6;
    u16* orow = xt + ((size_t)b_rel * 4096 + oh * 64 + ow) * 1024;
    const float* xb = x + (size_t)b * 256 * 16384 + (2 * oh) * 128 + 2 * ow;
    for (int ci = ci0; ci < 256; ci += 4) {
        const float* p = xb + (size_t)ci * 16384;
        const float2 t0 = *(const float2*)p;          // kh=0: kw=0,1
        const float2 t1 = *(const float2*)(p + 128);  // kh=1: kw=0,1
        *(ushort4*)(orow + ci * 4) =
            make_ushort4(f2bs(t0.x), f2bs(t0.y), f2bs(t1.x), f2bs(t1.y));
    }
}

// ---------------------------------------------------------------------------
// MFMA GEMM (m97-style gemm_bt): C[m][n] = sum_k A[m][k] * Bt[n][k]
//   A fp32 [M][K] (weights, converted to bf16 in-kernel while staging),
//   Bt bf16-bits [N][K] row-major along K (global_load_lds 16B staging).
//   128x128 tile, 4 waves in 2x2, each wave 4x4 grid of 16x16x32 MFMA.
//   Epilogue: BN scale/shift (+optional ReLU), out[((b*CO+m)*4096)+s],
//   b = b_base + (n>>12), s = n&4095.
// ---------------------------------------------------------------------------
template <int K, bool RELU, bool OUT_BF16>
__global__ __launch_bounds__(256) void k_gemm_bt(
    const float* __restrict__ A, const u16* __restrict__ Bt,
    const float* __restrict__ gamma, const float* __restrict__ beta,
    void* __restrict__ outv, int CO, int b_base)
{
    __shared__ u16 sA[128][32];
    __shared__ u16 sB[128][32];
    const int tid = threadIdx.x;
    const int lane = tid & 63, wave = tid >> 6;
    const int wm = (wave >> 1) * 64, wn = (wave & 1) * 64;
    const int l15 = lane & 15, q = lane >> 4;
    const int m0 = blockIdx.x * 128, n0 = blockIdx.y * 128;

    f32x4 acc[4][4];
    #pragma unroll
    for (int mi = 0; mi < 4; ++mi)
        #pragma unroll
        for (int ni = 0; ni < 4; ++ni) acc[mi][ni] = (f32x4){0.f, 0.f, 0.f, 0.f};

    for (int k0 = 0; k0 < K; k0 += 32) {
        // A tile [128 m][32 k]: fp32 load -> bf16 cvt -> ds_write 8B
        #pragma unroll
        for (int i = 0; i < 4; ++i) {
            const int e = tid + i * 256;           // [0,1024)
            const int ml = e >> 3, c4 = (e & 7) * 4;
            const float4 av = *(const float4*)(A + (size_t)(m0 + ml) * K + k0 + c4);
            *(ushort4*)&sA[ml][c4] =
                make_ushort4(f2bs(av.x), f2bs(av.y), f2bs(av.z), f2bs(av.w));
        }
        // B tile [128 n][32 k]: async 16B direct-to-LDS
        #pragma unroll
        for (int i = 0; i < 2; ++i) {
            const int e = tid + i * 256;           // [0,512)
            const int nl = e >> 2, ch = e & 3;
            gl_lds16(Bt + (size_t)(n0 + nl) * K + k0 + ch * 8, &sB[0][0] + (size_t)e * 8);
        }
        __syncthreads();
        short8 af[4], bf[4];
        #pragma unroll
        for (int mi = 0; mi < 4; ++mi) af[mi] = *(const short8*)&sA[wm + mi * 16 + l15][q * 8];
        #pragma unroll
        for (int ni = 0; ni < 4; ++ni) bf[ni] = *(const short8*)&sB[wn + ni * 16 + l15][q * 8];
        #pragma unroll
        for (int mi = 0; mi < 4; ++mi)
            #pragma unroll
            for (int ni = 0; ni < 4; ++ni)
                acc[mi][ni] = __builtin_amdgcn_mfma_f32_16x16x32_bf16(
                    af[mi], bf[ni], acc[mi][ni], 0, 0, 0);
        __syncthreads();
    }

    const float inv = rsqrtf(1.0f + BN_EPS);
    #pragma unroll
    for (int mi = 0; mi < 4; ++mi) {
        #pragma unroll
        for (int r = 0; r < 4; ++r) {
            const int m = m0 + wm + mi * 16 + q * 4 + r;   // C/D row = quad*4+reg
            const float sc = gamma[m] * inv, bb = beta[m];
            #pragma unroll
            for (int ni = 0; ni < 4; ++ni) {
                const int n = n0 + wn + ni * 16 + l15;     // C/D col = lane&15
                const int b = b_base + (n >> 12), s = n & 4095;
                float v = acc[mi][ni][r] * sc + bb;
                if (RELU) v = fmaxf(v, 0.f);
                const size_t oi = ((size_t)(b * CO + m)) * 4096 + s;
                if (OUT_BF16) ((bf16*)outv)[oi] = f2b(v);
                else          ((float*)outv)[oi] = v;
            }
        }
    }
}

// ---------------------------------------------------------------------------
// Axial attention (unchanged math from the passing round; stores now go to
// vcatT[b*4096+s][c] so proj's B-operand is row-major along K=channels).
// ---------------------------------------------------------------------------
template <int MODE>
__global__ __launch_bounds__(256) void k_attn(
    const bf16* __restrict__ qkv,     // [16,768,64,64]
    u16* __restrict__ vcatT)          // [65536][512] bf16 bits
{
    const int b   = blockIdx.x >> 6;
    const int fix = blockIdx.x & 63;
    const int tid = threadIdx.x;
    const int ty = tid >> 4, tx = tid & 15;

    const bf16* qb = qkv + (size_t)b * 768 * 4096;
    const bf16* kb = qb + 256 * 4096;
    const bf16* vb = qb + 512 * 4096;

    __shared__ float sS[64][64];
    __shared__ float sK[16][64];
    __shared__ float sQ[16][64];
    __shared__ float sV[64][65];

    float acc[4][4] = {};
    for (int cc0 = 0; cc0 < 256; cc0 += 16) {
        #pragma unroll
        for (int i = 0; i < 4; ++i) {
            const int e = tid + i * 256;
            const int c_l = e >> 6, ii = e & 63;
            const int c = cc0 + c_l;
            const int idx = (MODE == 0) ? (c * 4096 + fix * 64 + ii)
                                        : (c * 4096 + ii * 64 + fix);
            sK[c_l][ii] = b2f(kb[idx]);
            sQ[c_l][ii] = b2f(qb[idx]);
        }
        __syncthreads();
        #pragma unroll
        for (int cc = 0; cc < 16; ++cc) {
            const float4 kv = *(const float4*)&sK[cc][ty * 4];
            const float4 qv = *(const float4*)&sQ[cc][tx * 4];
            acc[0][0] += kv.x * qv.x; acc[0][1] += kv.x * qv.y; acc[0][2] += kv.x * qv.z; acc[0][3] += kv.x * qv.w;
            acc[1][0] += kv.y * qv.x; acc[1][1] += kv.y * qv.y; acc[1][2] += kv.y * qv.z; acc[1][3] += kv.y * qv.w;
            acc[2][0] += kv.z * qv.x; acc[2][1] += kv.z * qv.y; acc[2][2] += kv.z * qv.z; acc[2][3] += kv.z * qv.w;
            acc[3][0] += kv.w * qv.x; acc[3][1] += kv.w * qv.y; acc[3][2] += kv.w * qv.z; acc[3][3] += kv.w * qv.w;
        }
        __syncthreads();
    }
    #pragma unroll
    for (int i = 0; i < 4; ++i)
        #pragma unroll
        for (int j = 0; j < 4; ++j)
            sS[ty * 4 + i][tx * 4 + j] = acc[i][j] * 0.0625f;
    __syncthreads();

    if (tid < 64) {
        float m = -1e30f;
        for (int w = 0; w < 64; ++w) m = fmaxf(m, sS[w][tid]);
        float s = 0.f;
        for (int w = 0; w < 64; ++w) {
            const float e = __expf(sS[w][tid] - m);
            sS[w][tid] = e; s += e;
        }
        const float r = 1.0f / s;
        for (int w = 0; w < 64; ++w) sS[w][tid] *= r;
    }
    __syncthreads();

    for (int ch = 0; ch < 4; ++ch) {
        #pragma unroll
        for (int i = 0; i < 16; ++i) {
            const int e = tid + i * 256;
            const int c_l = e >> 6, ww = e & 63;
            const int c = ch * 64 + c_l;
            const int idx = (MODE == 0) ? (c * 4096 + fix * 64 + ww)
                                        : (c * 4096 + ww * 64 + fix);
            sV[c_l][ww] = b2f(vb[idx]);
        }
        __syncthreads();
        float o[4][4] = {};
        #pragma unroll
        for (int w = 0; w < 64; ++w) {
            const float v0 = sV[ty * 4 + 0][w];
            const float v1 = sV[ty * 4 + 1][w];
            const float v2 = sV[ty * 4 + 2][w];
            const float v3 = sV[ty * 4 + 3][w];
            const float4 pv = *(const float4*)&sS[w][tx * 4];
            o[0][0] += v0 * pv.x; o[0][1] += v0 * pv.y; o[0][2] += v0 * pv.z; o[0][3] += v0 * pv.w;
            o[1][0] += v1 * pv.x; o[1][1] += v1 * pv.y; o[1][2] += v1 * pv.z; o[1][3] += v1 * pv.w;
            o[2][0] += v2 * pv.x; o[2][1] += v2 * pv.y; o[2][2] += v2 * pv.z; o[2][3] += v2 * pv.w;
            o[3][0] += v3 * pv.x; o[3][1] += v3 * pv.y; o[3][2] += v3 * pv.z; o[3][3] += v3 * pv.w;
        }
        #pragma unroll
        for (int j = 0; j < 4; ++j) {
            const int qx = tx * 4 + j;
            const int s = (MODE == 0) ? (fix * 64 + qx) : (qx * 64 + fix);
            const int c0 = (MODE == 0 ? 0 : 256) + ch * 64 + ty * 4;
            *(ushort4*)&vcatT[((size_t)b * 4096 + s) * 512 + c0] =
                make_ushort4(f2bs(o[0][j]), f2bs(o[1][j]), f2bs(o[2][j]), f2bs(o[3][j]));
        }
        __syncthreads();
    }
}

// ---------------------------------------------------------------------------
extern "C" void kernel_launch(void* const* d_in, const int* in_sizes, int n_in,
                              void* d_out, int out_size, void* d_ws, size_t ws_size,
                              hipStream_t stream) {
    const float* x      = (const float*)d_in[0];
    const float* w_qkv  = (const float*)d_in[1];
    const float* gamma1 = (const float*)d_in[2];
    const float* beta1  = (const float*)d_in[3];
    const float* w_proj = (const float*)d_in[4];
    const float* gamma2 = (const float*)d_in[5];
    const float* beta2  = (const float*)d_in[6];
    float* out = (float*)d_out;

    // ws layout (160 MiB total, same peak as the passing round):
    //   [0, 64 MiB): xt half-batch [32768][1024] bf16, later reused as
    //                vcatT [65536][512] bf16 (xt is dead after conv).
    //   [64, 160 MiB): qkv [16][768][4096] bf16.
    u16* region = (u16*)d_ws;
    u16* xt     = region;
    u16* vcatT  = region;
    bf16* qkv   = (bf16*)((char*)d_ws + (size_t)64 * 1024 * 1024);

    // conv as two half-batch passes (keeps ws at 160 MiB, grid 6x256 each)
    k_patchify<<<512, 256, 0, stream>>>(x, xt, 0);
    k_gemm_bt<1024, false, true><<<dim3(6, 256), 256, 0, stream>>>(
        w_qkv, xt, gamma1, beta1, qkv, 768, 0);
    k_patchify<<<512, 256, 0, stream>>>(x, xt, 8);
    k_gemm_bt<1024, false, true><<<dim3(6, 256), 256, 0, stream>>>(
        w_qkv, xt, gamma1, beta1, qkv, 768, 8);

    k_attn<0><<<dim3(16 * 64), 256, 0, stream>>>(qkv, vcatT);
    k_attn<1><<<dim3(16 * 64), 256, 0, stream>>>(qkv, vcatT);

    k_gemm_bt<512, true, false><<<dim3(2, 512), 256, 0, stream>>>(
        w_proj, vcatT, gamma2, beta2, out, 256, 0);
}

// Round 4
// 862.165 us; speedup vs baseline: 2.8534x; 1.3970x over previous
//
#include <hip/hip_runtime.h>
#include <hip/hip_bf16.h>

typedef __hip_bfloat16 bf16;
typedef unsigned short u16;
typedef __attribute__((ext_vector_type(8))) short short8;
typedef __attribute__((ext_vector_type(4))) float f32x4;

#define BN_EPS 1e-5f

__device__ __forceinline__ float b2f(bf16 v) { return __bfloat162float(v); }
__device__ __forceinline__ u16 f2bs(float f) {
    bf16 h = __float2bfloat16(f);
    u16 s; __builtin_memcpy(&s, &h, 2); return s;
}
__device__ __forceinline__ void gl_lds16(const void* g, void* l) {
    __builtin_amdgcn_global_load_lds(
        (const __attribute__((address_space(1))) unsigned int*)g,
        (__attribute__((address_space(3))) unsigned int*)l, 16, 0, 0);
}

// ---------------------------------------------------------------------------
// Patchify: x fp32 [16,256,128,128] -> xt bf16 [n][k] for half a batch.
//   n = (b-b_base)*4096 + oh*64 + ow, k = ci*4 + kh*2 + kw (1024).
// ---------------------------------------------------------------------------
__global__ __launch_bounds__(256) void k_patchify(
    const float* __restrict__ x, u16* __restrict__ xt, int b_base)
{
    const int blk = blockIdx.x;              // 512 = 8 b * 64 oh
    const int b_rel = blk >> 6, oh = blk & 63;
    const int b = b_base + b_rel;
    const int ow = threadIdx.x & 63, ci0 = threadIdx.x >> 6;
    u16* orow = xt + ((size_t)b_rel * 4096 + oh * 64 + ow) * 1024;
    const float* xb = x + (size_t)b * 256 * 16384 + (2 * oh) * 128 + 2 * ow;
    for (int ci = ci0; ci < 256; ci += 4) {
        const float* p = xb + (size_t)ci * 16384;
        const float2 t0 = *(const float2*)p;
        const float2 t1 = *(const float2*)(p + 128);
        *(ushort4*)(orow + ci * 4) =
            make_ushort4(f2bs(t0.x), f2bs(t0.y), f2bs(t1.x), f2bs(t1.y));
    }
}

// ---------------------------------------------------------------------------
// Conv GEMM: C[m=pos][n=co] = sum_k xt[pos][k] * w[co][k], +BN, writes
// qkvT[b][s][co] (co contiguous).  A=xt via global_load_lds, B=w fp32->bf16.
// Grid (256 m-blocks, 6 n-blocks), half batch (32768 pos rows).
// ---------------------------------------------------------------------------
__global__ __launch_bounds__(256) void k_conv_gemm(
    const u16* __restrict__ xt, const float* __restrict__ w,
    const float* __restrict__ gamma, const float* __restrict__ beta,
    u16* __restrict__ qkvT, int b_base)
{
    __shared__ u16 sA[128][32];   // xt tile [pos][k]
    __shared__ u16 sB[128][32];   // w  tile [co][k]
    const int tid = threadIdx.x;
    const int lane = tid & 63, wave = tid >> 6;
    const int wm = (wave >> 1) * 64, wn = (wave & 1) * 64;
    const int l15 = lane & 15, q = lane >> 4;
    const int m0 = blockIdx.x * 128, n0 = blockIdx.y * 128;

    f32x4 acc[4][4];
    #pragma unroll
    for (int mi = 0; mi < 4; ++mi)
        #pragma unroll
        for (int ni = 0; ni < 4; ++ni) acc[mi][ni] = (f32x4){0.f, 0.f, 0.f, 0.f};

    for (int k0 = 0; k0 < 1024; k0 += 32) {
        #pragma unroll
        for (int i = 0; i < 2; ++i) {            // xt: async 16B
            const int e = tid + i * 256;         // [0,512)
            const int ml = e >> 2, ch = e & 3;
            gl_lds16(xt + (size_t)(m0 + ml) * 1024 + k0 + ch * 8,
                     &sA[0][0] + (size_t)e * 8);
        }
        #pragma unroll
        for (int i = 0; i < 4; ++i) {            // w: fp32 -> bf16
            const int e = tid + i * 256;         // [0,1024)
            const int cl = e >> 3, c4 = (e & 7) * 4;
            const float4 av = *(const float4*)(w + (size_t)(n0 + cl) * 1024 + k0 + c4);
            *(ushort4*)&sB[cl][c4] =
                make_ushort4(f2bs(av.x), f2bs(av.y), f2bs(av.z), f2bs(av.w));
        }
        __syncthreads();
        short8 af[4], bf[4];
        #pragma unroll
        for (int mi = 0; mi < 4; ++mi) af[mi] = *(const short8*)&sA[wm + mi * 16 + l15][q * 8];
        #pragma unroll
        for (int ni = 0; ni < 4; ++ni) bf[ni] = *(const short8*)&sB[wn + ni * 16 + l15][q * 8];
        #pragma unroll
        for (int mi = 0; mi < 4; ++mi)
            #pragma unroll
            for (int ni = 0; ni < 4; ++ni)
                acc[mi][ni] = __builtin_amdgcn_mfma_f32_16x16x32_bf16(
                    af[mi], bf[ni], acc[mi][ni], 0, 0, 0);
        __syncthreads();
    }

    const float inv = rsqrtf(1.0f + BN_EPS);
    float sc[4], bt[4]; int co[4];
    #pragma unroll
    for (int ni = 0; ni < 4; ++ni) {
        co[ni] = n0 + wn + ni * 16 + l15;       // C/D col = lane&15
        sc[ni] = gamma[co[ni]] * inv;
        bt[ni] = beta[co[ni]];
    }
    #pragma unroll
    for (int mi = 0; mi < 4; ++mi) {
        #pragma unroll
        for (int r = 0; r < 4; ++r) {
            const int pos = m0 + wm + mi * 16 + q * 4 + r;  // C/D row = quad*4+reg
            const int b = b_base + (pos >> 12), s = pos & 4095;
            u16* row = qkvT + ((size_t)(b * 4096 + s)) * 768;
            #pragma unroll
            for (int ni = 0; ni < 4; ++ni)
                row[co[ni]] = f2bs(acc[mi][ni][r] * sc[ni] + bt[ni]);
        }
    }
}

// ---------------------------------------------------------------------------
// MFMA axial attention.  qkvT[b][s][c] (c contig: 0..255 Q, 256..511 K,
// 512..767 V).  Per block (b,fix): S=K^T Q (64x64,K=256) -> reg softmax ->
// P,V through LDS -> O=V.P (256x64,K=64) -> vcatT[s][c].
//   MODE 0: row(i)=fix*64+i, out s=fix*64+qx, channels 0..255.
//   MODE 1: row(i)=i*64+fix, out s=qx*64+fix, channels 256..511.
// ---------------------------------------------------------------------------
template <int MODE>
__global__ __launch_bounds__(256) void k_attn_mfma(
    const u16* __restrict__ qkvT, u16* __restrict__ vcatT)
{
    const int b = blockIdx.x >> 6, fix = blockIdx.x & 63;
    const int tid = threadIdx.x, lane = tid & 63, wv = tid >> 6;
    const int l15 = lane & 15, q = lane >> 4;
    const u16* base = qkvT + (size_t)b * 4096 * 768;

    __shared__ u16 sV[256][72];   // V transposed: [c][w], pad 72 (2-way only)
    __shared__ u16 sP[64][72];    // probs: [qx][ky]

    // ---- V transpose: global [w][c-contig] -> LDS [c][w] ----
    {
        const int w = tid & 63, cg = tid >> 6;
        const int vrow_i = (MODE == 0) ? (fix * 64 + w) : (w * 64 + fix);
        const u16* vrow = base + (size_t)vrow_i * 768 + 512;
        #pragma unroll
        for (int it = 0; it < 8; ++it) {
            const int c0 = (cg + it * 4) * 8;
            const ushort4 lo = *(const ushort4*)(vrow + c0);
            const ushort4 hi = *(const ushort4*)(vrow + c0 + 4);
            sV[c0 + 0][w] = lo.x; sV[c0 + 1][w] = lo.y;
            sV[c0 + 2][w] = lo.z; sV[c0 + 3][w] = lo.w;
            sV[c0 + 4][w] = hi.x; sV[c0 + 5][w] = hi.y;
            sV[c0 + 6][w] = hi.z; sV[c0 + 7][w] = hi.w;
        }
    }

    // ---- Phase A: S[ky][qx] = sum_c K[c][ky] Q[c][qx].  Wave wv owns
    //      n-tile wv (qx block), all 4 m-tiles (full ky for softmax). ----
    f32x4 accS[4];
    #pragma unroll
    for (int t = 0; t < 4; ++t) accS[t] = (f32x4){0.f, 0.f, 0.f, 0.f};
    {
        const int qx = wv * 16 + l15;
        const u16* qrow = base + (size_t)((MODE == 0) ? (fix * 64 + qx) : (qx * 64 + fix)) * 768;
        const u16* krow[4];
        #pragma unroll
        for (int t = 0; t < 4; ++t) {
            const int ky = t * 16 + l15;
            krow[t] = base + (size_t)((MODE == 0) ? (fix * 64 + ky) : (ky * 64 + fix)) * 768 + 256;
        }
        for (int k0 = 0; k0 < 256; k0 += 32) {
            const short8 bq = *(const short8*)(qrow + k0 + q * 8);
            #pragma unroll
            for (int t = 0; t < 4; ++t) {
                const short8 ak = *(const short8*)(krow[t] + k0 + q * 8);
                accS[t] = __builtin_amdgcn_mfma_f32_16x16x32_bf16(ak, bq, accS[t], 0, 0, 0);
            }
        }
    }

    // ---- register softmax over ky (16 in-lane vals x 4 quad-lanes) ----
    {
        float m = -1e30f;
        #pragma unroll
        for (int t = 0; t < 4; ++t)
            #pragma unroll
            for (int r = 0; r < 4; ++r) m = fmaxf(m, accS[t][r]);
        m = fmaxf(m, __shfl_xor(m, 16, 64));
        m = fmaxf(m, __shfl_xor(m, 32, 64));
        m *= 0.0625f;
        float sum = 0.f;
        #pragma unroll
        for (int t = 0; t < 4; ++t)
            #pragma unroll
            for (int r = 0; r < 4; ++r) {
                const float e = __expf(accS[t][r] * 0.0625f - m);
                accS[t][r] = e; sum += e;
            }
        sum += __shfl_xor(sum, 16, 64);
        sum += __shfl_xor(sum, 32, 64);
        const float rinv = 1.0f / sum;
        const int qx = wv * 16 + l15;
        #pragma unroll
        for (int t = 0; t < 4; ++t) {
            // lane holds ky = t*16 + q*4 + r (C/D row), fixed qx (C/D col)
            *(ushort4*)&sP[qx][t * 16 + q * 4] = make_ushort4(
                f2bs(accS[t][0] * rinv), f2bs(accS[t][1] * rinv),
                f2bs(accS[t][2] * rinv), f2bs(accS[t][3] * rinv));
        }
    }
    __syncthreads();   // sV + sP ready

    // ---- Phase B: O[c][qx] = sum_w V[c][w] P[w][qx].  Wave wv owns
    //      c-tiles 4wv..4wv+3, all 4 qx-tiles. ----
    f32x4 accO[4][4];
    #pragma unroll
    for (int mi = 0; mi < 4; ++mi)
        #pragma unroll
        for (int ni = 0; ni < 4; ++ni) accO[mi][ni] = (f32x4){0.f, 0.f, 0.f, 0.f};
    #pragma unroll
    for (int k0 = 0; k0 < 64; k0 += 32) {
        short8 av[4], bp[4];
        #pragma unroll
        for (int mi = 0; mi < 4; ++mi) av[mi] = *(const short8*)&sV[wv * 64 + mi * 16 + l15][k0 + q * 8];
        #pragma unroll
        for (int ni = 0; ni < 4; ++ni) bp[ni] = *(const short8*)&sP[ni * 16 + l15][k0 + q * 8];
        #pragma unroll
        for (int mi = 0; mi < 4; ++mi)
            #pragma unroll
            for (int ni = 0; ni < 4; ++ni)
                accO[mi][ni] = __builtin_amdgcn_mfma_f32_16x16x32_bf16(
                    av[mi], bp[ni], accO[mi][ni], 0, 0, 0);
    }

    #pragma unroll
    for (int ni = 0; ni < 4; ++ni) {
        const int qx = ni * 16 + l15;
        const int s = (MODE == 0) ? (fix * 64 + qx) : (qx * 64 + fix);
        u16* orow = vcatT + ((size_t)b * 4096 + s) * 512 + (MODE == 0 ? 0 : 256);
        #pragma unroll
        for (int mi = 0; mi < 4; ++mi) {
            const int c = wv * 64 + mi * 16 + q * 4;   // + r along contiguous c
            *(ushort4*)(orow + c) = make_ushort4(
                f2bs(accO[mi][ni][0]), f2bs(accO[mi][ni][1]),
                f2bs(accO[mi][ni][2]), f2bs(accO[mi][ni][3]));
        }
    }
}

// ---------------------------------------------------------------------------
// Proj GEMM (unchanged anchor): C[m=co][n=s] = sum_c wp[co][c]*vcatT[s][c],
// +BN+ReLU, fp32 out[b][co][s].
// ---------------------------------------------------------------------------
__global__ __launch_bounds__(256) void k_proj(
    const float* __restrict__ A, const u16* __restrict__ Bt,
    const float* __restrict__ gamma, const float* __restrict__ beta,
    float* __restrict__ out)
{
    __shared__ u16 sA[128][32];
    __shared__ u16 sB[128][32];
    const int tid = threadIdx.x;
    const int lane = tid & 63, wave = tid >> 6;
    const int wm = (wave >> 1) * 64, wn = (wave & 1) * 64;
    const int l15 = lane & 15, q = lane >> 4;
    const int m0 = blockIdx.x * 128, n0 = blockIdx.y * 128;

    f32x4 acc[4][4];
    #pragma unroll
    for (int mi = 0; mi < 4; ++mi)
        #pragma unroll
        for (int ni = 0; ni < 4; ++ni) acc[mi][ni] = (f32x4){0.f, 0.f, 0.f, 0.f};

    for (int k0 = 0; k0 < 512; k0 += 32) {
        #pragma unroll
        for (int i = 0; i < 4; ++i) {
            const int e = tid + i * 256;
            const int ml = e >> 3, c4 = (e & 7) * 4;
            const float4 av = *(const float4*)(A + (size_t)(m0 + ml) * 512 + k0 + c4);
            *(ushort4*)&sA[ml][c4] =
                make_ushort4(f2bs(av.x), f2bs(av.y), f2bs(av.z), f2bs(av.w));
        }
        #pragma unroll
        for (int i = 0; i < 2; ++i) {
            const int e = tid + i * 256;
            const int nl = e >> 2, ch = e & 3;
            gl_lds16(Bt + (size_t)(n0 + nl) * 512 + k0 + ch * 8, &sB[0][0] + (size_t)e * 8);
        }
        __syncthreads();
        short8 af[4], bf[4];
        #pragma unroll
        for (int mi = 0; mi < 4; ++mi) af[mi] = *(const short8*)&sA[wm + mi * 16 + l15][q * 8];
        #pragma unroll
        for (int ni = 0; ni < 4; ++ni) bf[ni] = *(const short8*)&sB[wn + ni * 16 + l15][q * 8];
        #pragma unroll
        for (int mi = 0; mi < 4; ++mi)
            #pragma unroll
            for (int ni = 0; ni < 4; ++ni)
                acc[mi][ni] = __builtin_amdgcn_mfma_f32_16x16x32_bf16(
                    af[mi], bf[ni], acc[mi][ni], 0, 0, 0);
        __syncthreads();
    }

    const float inv = rsqrtf(1.0f + BN_EPS);
    #pragma unroll
    for (int mi = 0; mi < 4; ++mi) {
        #pragma unroll
        for (int r = 0; r < 4; ++r) {
            const int m = m0 + wm + mi * 16 + q * 4 + r;
            const float sc = gamma[m] * inv, bb = beta[m];
            #pragma unroll
            for (int ni = 0; ni < 4; ++ni) {
                const int n = n0 + wn + ni * 16 + l15;
                const int b = n >> 12, s = n & 4095;
                const float v = acc[mi][ni][r] * sc + bb;
                out[((size_t)(b * 256 + m)) * 4096 + s] = fmaxf(v, 0.f);
            }
        }
    }
}

// ---------------------------------------------------------------------------
extern "C" void kernel_launch(void* const* d_in, const int* in_sizes, int n_in,
                              void* d_out, int out_size, void* d_ws, size_t ws_size,
                              hipStream_t stream) {
    const float* x      = (const float*)d_in[0];
    const float* w_qkv  = (const float*)d_in[1];
    const float* gamma1 = (const float*)d_in[2];
    const float* beta1  = (const float*)d_in[3];
    const float* w_proj = (const float*)d_in[4];
    const float* gamma2 = (const float*)d_in[5];
    const float* beta2  = (const float*)d_in[6];
    float* out = (float*)d_out;

    // ws: [0,64MiB) xt half-batch [32768][1024] bf16, reused as vcatT
    //     [65536][512]; [64,160MiB) qkvT [16][4096][768] bf16.
    u16* xt    = (u16*)d_ws;
    u16* vcatT = (u16*)d_ws;
    u16* qkvT  = (u16*)((char*)d_ws + (size_t)64 * 1024 * 1024);

    k_patchify<<<512, 256, 0, stream>>>(x, xt, 0);
    k_conv_gemm<<<dim3(256, 6), 256, 0, stream>>>(xt, w_qkv, gamma1, beta1, qkvT, 0);
    k_patchify<<<512, 256, 0, stream>>>(x, xt, 8);
    k_conv_gemm<<<dim3(256, 6), 256, 0, stream>>>(xt, w_qkv, gamma1, beta1, qkvT, 8);

    k_attn_mfma<0><<<dim3(16 * 64), 256, 0, stream>>>(qkvT, vcatT);
    k_attn_mfma<1><<<dim3(16 * 64), 256, 0, stream>>>(qkvT, vcatT);

    k_proj<<<dim3(2, 512), 256, 0, stream>>>(w_proj, vcatT, gamma2, beta2, out);
}